// Round 4
// baseline (220.117 us; speedup 1.0000x reference)
//
#include <hip/hip_runtime.h>
#include <hip/hip_bf16.h>
#include <stdint.h>

#define B_ 8
#define S_ 2048
#define D_ 128
#define QBLK 64
#define KVB 32
#define NWAVE 4
#define VSTRIDE 40   // padded f16 stride for transposed V / P tiles (80B = 20 banks -> ~2-way, free)

typedef _Float16 f16;
typedef f16 f16x8 __attribute__((ext_vector_type(8)));
typedef f16 f16x4 __attribute__((ext_vector_type(4)));
typedef f16 f16x2 __attribute__((ext_vector_type(2)));
typedef float f32x4 __attribute__((ext_vector_type(4)));

__global__ __launch_bounds__(256) void attn_fwd(const float* __restrict__ Q,
                                                const float* __restrict__ K,
                                                const float* __restrict__ V,
                                                const void* __restrict__ Mp,
                                                float* __restrict__ O) {
  const int t = threadIdx.x;
  const int b = blockIdx.y;
  const int q0 = blockIdx.x * QBLK;
  const int w = t >> 6;        // wave id 0..3
  const int l = t & 63;        // lane
  const int l15 = l & 15;
  const int lg = l >> 4;       // 16-lane group 0..3

  // ---- mask dtype detection (int32 / uint8-bool / float32) ----
  const uint32_t* mw = (const uint32_t*)Mp;
  int oki = 1, okf = 1;
#pragma unroll
  for (int i = 0; i < 4; ++i) {
    uint32_t x = mw[t * 4 + i];
    oki &= (x <= 1u) ? 1 : 0;
    okf &= (x == 0u || x == 0x3f800000u) ? 1 : 0;
  }
  const int alli = __syncthreads_and(oki);
  const int allf = __syncthreads_and(okf);
  const int mode = alli ? 0 : (allf ? 2 : 1);  // 0=int32, 1=uint8, 2=float32
  const int*     mi32 = (const int*)Mp + b * S_;
  const uint8_t* mu8  = (const uint8_t*)Mp + b * S_;
  const float*   mf32 = (const float*)Mp + b * S_;

  // K tile: [KVB][128] f16, XOR-swizzled (row-major [32][128] f16 would be 32-way bank conflict)
  __shared__ alignas(16) f16 Klds[KVB * 128];
  // V^T tile: [128][VSTRIDE] f16 (Vt[d][key])
  __shared__ alignas(16) f16 Vt[128 * VSTRIDE];
  // Per-wave P tile: [16 rows][VSTRIDE]
  __shared__ alignas(16) f16 Plds[NWAVE][16 * VSTRIDE];

  // ---- Q fragments in registers: A-operand row m = l15, k = lg*8 + j + 32*kt ----
  f16x8 qf[4];
  {
    const int qrow = q0 + 16 * w + l15;
    const float* qp = Q + ((size_t)b * S_ + qrow) * D_ + lg * 8;
#pragma unroll
    for (int kt = 0; kt < 4; ++kt) {
      float4 a = *(const float4*)(qp + 32 * kt);
      float4 c = *(const float4*)(qp + 32 * kt + 4);
      qf[kt] = (f16x8){(f16)a.x, (f16)a.y, (f16)a.z, (f16)a.w,
                       (f16)c.x, (f16)c.y, (f16)c.z, (f16)c.w};
    }
  }

  f32x4 acco[8];
#pragma unroll
  for (int dt = 0; dt < 8; ++dt) acco[dt] = (f32x4){0.f, 0.f, 0.f, 0.f};
  // Running max over UNMASKED keys only (exact: the shift cancels in P/sum(P);
  // using the all-keys max like the reference text would put p in f16-denormal
  // range whenever the argmax key is masked -> the 0.95 absmax failure).
  float m_r[4], l_r[4];
#pragma unroll
  for (int r = 0; r < 4; ++r) { m_r[r] = -1e30f; l_r[r] = 0.f; }

  for (int kv0 = 0; kv0 < S_; kv0 += KVB) {
    // ---- stage K tile (fp32 -> f16, XOR-swizzled row-major) ----
    {
      const int c4 = t & 31;  // float4 column
#pragma unroll
      for (int pass = 0; pass < 4; ++pass) {
        const int row = (t >> 5) + 8 * pass;  // 0..31
        float4 kvv = *(const float4*)(K + ((size_t)b * S_ + kv0 + row) * D_ + c4 * 4);
        const int idx = (row * 128 + c4 * 4) ^ ((row & 7) << 3);
        *(f16x4*)(&Klds[idx]) = (f16x4){(f16)kvv.x, (f16)kvv.y, (f16)kvv.z, (f16)kvv.w};
      }
    }
    // ---- stage V tile transposed: Vt[d][key] ----
    {
      const int c = t >> 3;  // 0..31 -> d = 4c..4c+3
#pragma unroll
      for (int pass = 0; pass < 2; ++pass) {
        const int kp = (t & 7) + 8 * pass;  // key pair 0..15
        const float* vp = V + ((size_t)b * S_ + kv0 + 2 * kp) * D_ + c * 4;
        float4 v0 = *(const float4*)(vp);
        float4 v1 = *(const float4*)(vp + D_);
#pragma unroll
        for (int i = 0; i < 4; ++i) {
          f16x2 pk = {(f16)(&v0.x)[i], (f16)(&v1.x)[i]};
          *(f16x2*)(&Vt[(4 * c + i) * VSTRIDE + 2 * kp]) = pk;
        }
      }
    }
    __syncthreads();

    // ---- QK^T: S[16 rows][32 keys] per wave ----
    f32x4 sacc[2];
    sacc[0] = (f32x4){0.f, 0.f, 0.f, 0.f};
    sacc[1] = (f32x4){0.f, 0.f, 0.f, 0.f};
#pragma unroll
    for (int nt = 0; nt < 2; ++nt) {
      const int key = l15 + 16 * nt;
#pragma unroll
      for (int kt = 0; kt < 4; ++kt) {
        const int idx = (key * 128 + lg * 8 + 32 * kt) ^ ((key & 7) << 3);
        f16x8 kf = *(const f16x8*)(&Klds[idx]);
        sacc[nt] = __builtin_amdgcn_mfma_f32_16x16x32_f16(qf[kt], kf, sacc[nt], 0, 0, 0);
      }
    }

    // ---- mask bits for this lane's two key columns (true = key participates) ----
    const int key0 = kv0 + l15, key1 = kv0 + l15 + 16;
    bool u0, u1;
    if (mode == 0)      { u0 = (mi32[key0] == 0);  u1 = (mi32[key1] == 0); }
    else if (mode == 1) { u0 = (mu8[key0] == 0);   u1 = (mu8[key1] == 0); }
    else                { u0 = (mf32[key0] == 0.f); u1 = (mf32[key1] == 0.f); }

    // ---- online softmax over UNMASKED keys ----
#pragma unroll
    for (int r = 0; r < 4; ++r) {
      const float s0 = sacc[0][r], s1 = sacc[1][r];
      float tm = fmaxf(u0 ? s0 : -1e30f, u1 ? s1 : -1e30f);
#pragma unroll
      for (int sh = 1; sh < 16; sh <<= 1) tm = fmaxf(tm, __shfl_xor(tm, sh));
      const float mn = fmaxf(m_r[r], tm);
      const float scale = __expf(m_r[r] - mn);
      // select BEFORE any use: speculative exp(+huge)=inf is discarded, never multiplied
      const float p0 = u0 ? __expf(s0 - mn) : 0.f;
      const float p1 = u1 ? __expf(s1 - mn) : 0.f;
      float rs = p0 + p1;
#pragma unroll
      for (int sh = 1; sh < 16; sh <<= 1) rs += __shfl_xor(rs, sh);
      l_r[r] = l_r[r] * scale + rs;
      m_r[r] = mn;
#pragma unroll
      for (int dt = 0; dt < 8; ++dt) acco[dt][r] *= scale;
      const int prow = lg * 4 + r;
      Plds[w][prow * VSTRIDE + l15]      = (f16)p0;   // p in [0,1]: f16-safe
      Plds[w][prow * VSTRIDE + l15 + 16] = (f16)p1;
    }

    // ---- PV: A = P (m=l15, k=lg*8+j), B = V^T (k=lg*8+j keys, n=l15+16dt) ----
    f16x8 pa = *(const f16x8*)(&Plds[w][l15 * VSTRIDE + lg * 8]);
#pragma unroll
    for (int dt = 0; dt < 8; ++dt) {
      f16x8 vf = *(const f16x8*)(&Vt[(l15 + 16 * dt) * VSTRIDE + lg * 8]);
      acco[dt] = __builtin_amdgcn_mfma_f32_16x16x32_f16(pa, vf, acco[dt], 0, 0, 0);
    }
    __syncthreads();
  }

  // ---- epilogue: O = acc / l ----
#pragma unroll
  for (int r = 0; r < 4; ++r) {
    const float inv = 1.0f / l_r[r];
    const int qrow = q0 + 16 * w + lg * 4 + r;
    float* op = O + ((size_t)b * S_ + qrow) * D_ + l15;
#pragma unroll
    for (int dt = 0; dt < 8; ++dt) op[16 * dt] = acco[dt][r] * inv;
  }
}

extern "C" void kernel_launch(void* const* d_in, const int* in_sizes, int n_in,
                              void* d_out, int out_size, void* d_ws, size_t ws_size,
                              hipStream_t stream) {
  const float* q = (const float*)d_in[0];
  const float* k = (const float*)d_in[1];
  const float* v = (const float*)d_in[2];
  const void*  m = d_in[3];
  float* o = (float*)d_out;
  dim3 grid(S_ / QBLK, B_);
  dim3 block(256);
  attn_fwd<<<grid, block, 0, stream>>>(q, k, v, m, o);
}

// Round 5
// 170.680 us; speedup vs baseline: 1.2896x; 1.2896x over previous
//
#include <hip/hip_runtime.h>
#include <hip/hip_bf16.h>
#include <stdint.h>

#define B_ 8
#define S_ 2048
#define D_ 128
#define QBLK 32
#define KVB 32
#define SHALF 1024
#define NIT (SHALF / KVB)   // 32
#define VSTRIDE 40          // padded f16 stride for V^T / P tiles

typedef _Float16 f16;
typedef f16 f16x8 __attribute__((ext_vector_type(8)));
typedef f16 f16x4 __attribute__((ext_vector_type(4)));
typedef f16 f16x2 __attribute__((ext_vector_type(2)));
typedef float f32x4 __attribute__((ext_vector_type(4)));

// LDS (bytes):
//  [0     .. 16384)  Klds: 2 kv-halves x [32 rows][128] f16, XOR-swizzled
//  [16384 .. 36864)  Vt:   2 kv-halves x [128 d][VSTRIDE] f16
//  [36864 .. 41984)  Plds: 4 waves x [16][VSTRIDE] f16
// epilogue reuse (after final barrier, all staging reads complete):
//  [0     .. 16896)  mrg: 2 rowgrps x [16 rows][132] f32   (kv-half-1 partial O)
//  [20480 .. 20736)  mlb: 2 rowgrps x [16 rows][2] f32     (m, l partials)

__global__ __launch_bounds__(256, 2) void attn_fwd(const float* __restrict__ Q,
                                                   const float* __restrict__ K,
                                                   const float* __restrict__ V,
                                                   const void* __restrict__ Mp,
                                                   float* __restrict__ O) {
  const int t = threadIdx.x;
  const int b = blockIdx.y;
  const int q0 = blockIdx.x * QBLK;
  const int w = t >> 6;
  const int l = t & 63;
  const int l15 = l & 15;
  const int lg = l >> 4;
  const int rowgrp = w & 1;   // q rows [16*rowgrp, 16*rowgrp+16)
  const int kvh = w >> 1;     // key half [kvh*1024, kvh*1024+1024)

  __shared__ alignas(16) char smem[41984];
  f16* Klds = (f16*)smem;
  f16* Vt   = (f16*)(smem + 16384);
  f16* Pl   = (f16*)(smem + 36864);
  float* mrg = (float*)smem;
  float* mlb = (float*)(smem + 20480);

  // ---- mask dtype detection (int32 / uint8-bool / float32), block-uniform ----
  const uint32_t* mw = (const uint32_t*)Mp;
  int oki = 1, okf = 1;
#pragma unroll
  for (int i = 0; i < 4; ++i) {
    uint32_t x = mw[t * 4 + i];
    oki &= (x <= 1u) ? 1 : 0;
    okf &= (x == 0u || x == 0x3f800000u) ? 1 : 0;
  }
  const int alli = __syncthreads_and(oki);
  const int allf = __syncthreads_and(okf);
  const int mode = alli ? 0 : (allf ? 2 : 1);
  const int*     mi32 = (const int*)Mp + b * S_;
  const uint8_t* mu8  = (const uint8_t*)Mp + b * S_;
  const float*   mf32 = (const float*)Mp + b * S_;

  // ---- Q fragments: A-operand row m = l15, k = lg*8 + j + 32*kt ----
  f16x8 qf[4];
  {
    const int qrow = q0 + 16 * rowgrp + l15;
    const float* qp = Q + ((size_t)b * S_ + qrow) * D_ + lg * 8;
#pragma unroll
    for (int kt = 0; kt < 4; ++kt) {
      float4 a = *(const float4*)(qp + 32 * kt);
      float4 c = *(const float4*)(qp + 32 * kt + 4);
      qf[kt] = (f16x8){(f16)a.x, (f16)a.y, (f16)a.z, (f16)a.w,
                       (f16)c.x, (f16)c.y, (f16)c.z, (f16)c.w};
    }
  }

  f32x4 acco[8];
#pragma unroll
  for (int dt = 0; dt < 8; ++dt) acco[dt] = (f32x4){0.f, 0.f, 0.f, 0.f};
  float m_r[4], l_r[4];
#pragma unroll
  for (int r = 0; r < 4; ++r) { m_r[r] = -1e30f; l_r[r] = 0.f; }

  // ---- staging geometry (both kv-halves staged cooperatively by all 256 threads) ----
  const float* Kb = K + (size_t)b * S_ * D_;
  const float* Vb = V + (size_t)b * S_ * D_;
  const int krow0 = t >> 5;        // K row base (rows krow0 + 8p, p=0..7; gr>>5 = half)
  const int kc4 = (t & 31) * 4;    // K col (element)
  const int vc = (t >> 3) * 4;     // V d base (elements vc..vc+3)
  const int vk7 = t & 7;           // V key-pair base

  float4 kreg[8], vreg[8];

#define LOADT(KV0)                                                                   \
  {                                                                                  \
    _Pragma("unroll") for (int p = 0; p < 8; ++p) {                                  \
      const int gr = krow0 + 8 * p;                                                  \
      const int half = gr >> 5, row = gr & 31;                                       \
      kreg[p] = *(const float4*)(Kb + (size_t)(half * SHALF + (KV0) + row) * D_ + kc4); \
    }                                                                                \
    _Pragma("unroll") for (int p = 0; p < 4; ++p) {                                  \
      const int kg = vk7 + 8 * p;                                                    \
      const int half = kg >> 4, kp = kg & 15;                                        \
      const float* vp = Vb + (size_t)(half * SHALF + (KV0) + 2 * kp) * D_ + vc;      \
      vreg[2 * p]     = *(const float4*)vp;                                          \
      vreg[2 * p + 1] = *(const float4*)(vp + D_);                                   \
    }                                                                                \
  }

  LOADT(0);

  for (int it = 0; it < NIT; ++it) {
    const int kv0 = it * KVB;
    // ---- convert + write staged regs to LDS ----
#pragma unroll
    for (int p = 0; p < 8; ++p) {
      const int gr = krow0 + 8 * p;
      const int half = gr >> 5, row = gr & 31;
      const int idx = half * 4096 + ((row * 128 + kc4) ^ ((row & 7) << 3));
      float4 kv = kreg[p];
      *(f16x4*)(Klds + idx) = (f16x4){(f16)kv.x, (f16)kv.y, (f16)kv.z, (f16)kv.w};
    }
#pragma unroll
    for (int p = 0; p < 4; ++p) {
      const int kg = vk7 + 8 * p;
      const int half = kg >> 4, kp = kg & 15;
      float4 v0 = vreg[2 * p], v1 = vreg[2 * p + 1];
#pragma unroll
      for (int i = 0; i < 4; ++i) {
        *(f16x2*)(Vt + half * 5120 + (vc + i) * VSTRIDE + 2 * kp) =
            (f16x2){(f16)(&v0.x)[i], (f16)(&v1.x)[i]};
      }
    }
    __syncthreads();

    // ---- prefetch next tile (T14: overlaps all of compute below) ----
    if (it + 1 < NIT) LOADT(kv0 + KVB);

    // ---- mask bits for this wave's two key columns ----
    const int keyb = kvh * SHALF + kv0;
    bool u0, u1;
    if (mode == 0)      { u0 = (mi32[keyb + l15] == 0);       u1 = (mi32[keyb + l15 + 16] == 0); }
    else if (mode == 1) { u0 = (mu8[keyb + l15] == 0);        u1 = (mu8[keyb + l15 + 16] == 0); }
    else                { u0 = (mf32[keyb + l15] == 0.f);     u1 = (mf32[keyb + l15 + 16] == 0.f); }

    // ---- QK^T on this wave's kv-half ----
    f32x4 sacc[2];
    sacc[0] = (f32x4){0.f, 0.f, 0.f, 0.f};
    sacc[1] = (f32x4){0.f, 0.f, 0.f, 0.f};
#pragma unroll
    for (int nt = 0; nt < 2; ++nt) {
      const int key = l15 + 16 * nt;
#pragma unroll
      for (int kt = 0; kt < 4; ++kt) {
        const int idx = kvh * 4096 + ((key * 128 + lg * 8 + 32 * kt) ^ ((key & 7) << 3));
        f16x8 kf = *(const f16x8*)(Klds + idx);
        sacc[nt] = __builtin_amdgcn_mfma_f32_16x16x32_f16(qf[kt], kf, sacc[nt], 0, 0, 0);
      }
    }

    // ---- online softmax over UNMASKED keys (shift cancels in P/sum; f16-safe p<=1) ----
#pragma unroll
    for (int r = 0; r < 4; ++r) {
      const float s0 = sacc[0][r], s1 = sacc[1][r];
      float tm = fmaxf(u0 ? s0 : -1e30f, u1 ? s1 : -1e30f);
#pragma unroll
      for (int sh = 1; sh < 16; sh <<= 1) tm = fmaxf(tm, __shfl_xor(tm, sh));
      const float mn = fmaxf(m_r[r], tm);
      const float scale = __expf(m_r[r] - mn);
      const float p0 = u0 ? __expf(s0 - mn) : 0.f;
      const float p1 = u1 ? __expf(s1 - mn) : 0.f;
      float rs = p0 + p1;
#pragma unroll
      for (int sh = 1; sh < 16; sh <<= 1) rs += __shfl_xor(rs, sh);
      l_r[r] = l_r[r] * scale + rs;
      m_r[r] = mn;
#pragma unroll
      for (int dt = 0; dt < 8; ++dt) acco[dt][r] *= scale;
      const int prow = lg * 4 + r;
      Pl[w * 640 + prow * VSTRIDE + l15]      = (f16)p0;
      Pl[w * 640 + prow * VSTRIDE + l15 + 16] = (f16)p1;
    }

    // ---- PV on this wave's kv-half ----
    f16x8 pa = *(const f16x8*)(Pl + w * 640 + l15 * VSTRIDE + lg * 8);
#pragma unroll
    for (int dt = 0; dt < 8; ++dt) {
      f16x8 vf = *(const f16x8*)(Vt + kvh * 5120 + (l15 + 16 * dt) * VSTRIDE + lg * 8);
      acco[dt] = __builtin_amdgcn_mfma_f32_16x16x32_f16(pa, vf, acco[dt], 0, 0, 0);
    }
    __syncthreads();
  }

  // ---- epilogue: merge kv-half partials (LDS reuse is safe past the final barrier) ----
  if (kvh == 1) {
#pragma unroll
    for (int r = 0; r < 4; ++r) {
      const int row = 4 * lg + r;
#pragma unroll
      for (int dt = 0; dt < 8; ++dt)
        mrg[rowgrp * 2112 + row * 132 + l15 + 16 * dt] = acco[dt][r];
      if (l15 == 0) {
        mlb[rowgrp * 32 + row * 2]     = m_r[r];
        mlb[rowgrp * 32 + row * 2 + 1] = l_r[r];
      }
    }
  }
  __syncthreads();
  if (kvh == 0) {
#pragma unroll
    for (int r = 0; r < 4; ++r) {
      const int row = 4 * lg + r;
      const float m2 = mlb[rowgrp * 32 + row * 2];
      const float l2 = mlb[rowgrp * 32 + row * 2 + 1];
      const float mm = fmaxf(m_r[r], m2);
      const float e1 = __expf(m_r[r] - mm);
      const float e2 = __expf(m2 - mm);
      const float inv = 1.0f / (l_r[r] * e1 + l2 * e2);
      const int qrow = q0 + 16 * rowgrp + row;
      float* op = O + ((size_t)b * S_ + qrow) * D_ + l15;
#pragma unroll
      for (int dt = 0; dt < 8; ++dt)
        op[16 * dt] = (acco[dt][r] * e1 + mrg[rowgrp * 2112 + row * 132 + l15 + 16 * dt] * e2) * inv;
    }
  }
}

extern "C" void kernel_launch(void* const* d_in, const int* in_sizes, int n_in,
                              void* d_out, int out_size, void* d_ws, size_t ws_size,
                              hipStream_t stream) {
  const float* q = (const float*)d_in[0];
  const float* k = (const float*)d_in[1];
  const float* v = (const float*)d_in[2];
  const void*  m = d_in[3];
  float* o = (float*)d_out;
  dim3 grid(S_ / QBLK, B_);
  dim3 block(256);
  attn_fwd<<<grid, block, 0, stream>>>(q, k, v, m, o);
}

// Round 11
// 132.592 us; speedup vs baseline: 1.6601x; 1.2873x over previous
//
#include <hip/hip_runtime.h>
#include <hip/hip_bf16.h>
#include <stdint.h>

#define B_ 8
#define S_ 2048
#define D_ 128
#define QBLK 64
#define KVB 32
#define SHALF 1024
#define NIT (SHALF / KVB)   // 32
#define VST 40              // padded f16 stride for V^T / P tiles

typedef _Float16 f16;
typedef f16 f16x8 __attribute__((ext_vector_type(8)));
typedef f16 f16x4 __attribute__((ext_vector_type(4)));
typedef f16 f16x2 __attribute__((ext_vector_type(2)));
typedef float f32x4 __attribute__((ext_vector_type(4)));

// 512 threads = 8 waves: rowgrp = w&3 (16 q-rows each), kvh = w>>2 (key half).
// LDS: [0,16384) Klds 2x[32][128] f16 swizzled | [16384,36864) Vt 2x[128][VST] f16
//      [36864,47104) Pl 8x[16][VST] f16 | [47104,47360) madd 64 f32
// epilogue overlay (all staging reads complete): mrg 4x[16][132] f32 @0,
//      mlb 4x[16][2] f32 @36864
__global__ __launch_bounds__(512, 2) void attn_fwd(const float* __restrict__ Q,
                                                   const float* __restrict__ K,
                                                   const float* __restrict__ V,
                                                   const void* __restrict__ Mp,
                                                   float* __restrict__ O) {
  const int t = threadIdx.x;
  const int b = blockIdx.y;
  const int q0 = blockIdx.x * QBLK;
  const int w = t >> 6, l = t & 63, l15 = l & 15, lg = l >> 4;
  const int rowgrp = w & 3, kvh = w >> 2;

  __shared__ alignas(16) char smem[47360];
  f16* Klds  = (f16*)smem;
  f16* Vt    = (f16*)(smem + 16384);
  f16* Pl    = (f16*)(smem + 36864);
  float* madd = (float*)(smem + 47104);
  float* mrg = (float*)smem;
  float* mlb = (float*)(smem + 36864);

  // ---- mask dtype detection (int32 / uint8-bool / float32), block-uniform ----
  const uint32_t* mw = (const uint32_t*)Mp;
  int oki = 1, okf = 1;
#pragma unroll
  for (int i = 0; i < 4; ++i) {
    uint32_t x = mw[t * 4 + i];
    oki &= (x <= 1u) ? 1 : 0;
    okf &= (x == 0u || x == 0x3f800000u) ? 1 : 0;
  }
  const int alli = __syncthreads_and(oki);
  const int allf = __syncthreads_and(okf);
  const int mode = alli ? 0 : (allf ? 2 : 1);
  const int*     mi32 = (const int*)Mp + b * S_;
  const uint8_t* mu8  = (const uint8_t*)Mp + b * S_;
  const float*   mf32 = (const float*)Mp + b * S_;

  // ---- Q fragments (B-operand of swapped QK): col n = l15 = qrow, k = lg*8+j+32kt ----
  f16x8 qf[4];
  {
    const int qrow = q0 + 16 * rowgrp + l15;
    const float* qp = Q + ((size_t)b * S_ + qrow) * D_ + lg * 8;
#pragma unroll
    for (int kt = 0; kt < 4; ++kt) {
      float4 a = *(const float4*)(qp + 32 * kt);
      float4 c = *(const float4*)(qp + 32 * kt + 4);
      qf[kt] = (f16x8){(f16)a.x, (f16)a.y, (f16)a.z, (f16)a.w,
                       (f16)c.x, (f16)c.y, (f16)c.z, (f16)c.w};
    }
  }

  f32x4 acco[8];
#pragma unroll
  for (int dt = 0; dt < 8; ++dt) acco[dt] = (f32x4){0.f, 0.f, 0.f, 0.f};
  float m_r = -1e30f, l_r = 0.f;  // per-lane state for qrow = l15 (replicated x4 lgs)

  // ---- staging geometry: 512 threads stage 64 keys (2 halves x 32) of K and V ----
  const float* Kb = K + (size_t)b * S_ * D_;
  const float* Vb = V + (size_t)b * S_ * D_;
  const int kc4 = (t & 31) * 4;   // K col
  const int kgr = t >> 5;         // K row group 0..15
  const int vc  = (t >> 4) * 4;   // V d base 0..124
  const int vkp = t & 15;         // V key-pair base

  float4 kreg[4], vreg[4];
  float mreg = 0.f;

#define LOADT(KV0)                                                                    \
  {                                                                                   \
    _Pragma("unroll") for (int p = 0; p < 4; ++p) {                                   \
      const int gr = kgr + 16 * p, half = gr >> 5, row = gr & 31;                     \
      kreg[p] = *(const float4*)(Kb + (size_t)(half * SHALF + (KV0) + row) * D_ + kc4); \
    }                                                                                 \
    _Pragma("unroll") for (int p = 0; p < 2; ++p) {                                   \
      const int kg = vkp + 16 * p, half = kg >> 4, kp = kg & 15;                      \
      const float* vp = Vb + (size_t)(half * SHALF + (KV0) + 2 * kp) * D_ + vc;       \
      vreg[2 * p]     = *(const float4*)vp;                                           \
      vreg[2 * p + 1] = *(const float4*)(vp + D_);                                    \
    }                                                                                 \
    if (t < 64) {                                                                     \
      const int gk = (t >> 5) * SHALF + (KV0) + (t & 31);                             \
      mreg = (mode == 0) ? (mi32[gk] ? 1.f : 0.f)                                     \
           : (mode == 1) ? (mu8[gk] ? 1.f : 0.f) : mf32[gk];                          \
    }                                                                                 \
  }

  LOADT(0);

  for (int it = 0; it < NIT; ++it) {
    const int kv0 = it * KVB;
    // ---- convert staged regs -> LDS ----
#pragma unroll
    for (int p = 0; p < 4; ++p) {
      const int gr = kgr + 16 * p, half = gr >> 5, row = gr & 31;
      const int idx = half * 4096 + ((row * 128 + kc4) ^ ((row & 7) << 3));
      float4 kv = kreg[p];
      *(f16x4*)(Klds + idx) = (f16x4){(f16)kv.x, (f16)kv.y, (f16)kv.z, (f16)kv.w};
    }
#pragma unroll
    for (int p = 0; p < 2; ++p) {
      const int kg = vkp + 16 * p, half = kg >> 4, kp = kg & 15;
      float4 v0 = vreg[2 * p], v1 = vreg[2 * p + 1];
#pragma unroll
      for (int i = 0; i < 4; ++i)
        *(f16x2*)(Vt + half * 5120 + (vc + i) * VST + 2 * kp) =
            (f16x2){(f16)(&v0.x)[i], (f16)(&v1.x)[i]};
    }
    if (t < 64) madd[t] = (mreg != 0.f) ? -1e30f : 0.f;
    __syncthreads();

    // ---- prefetch next tile (hides under QK/softmax/PV) ----
    if (it + 1 < NIT) LOADT(kv0 + KVB);

    // ---- swapped QK^T: sacc[nt][r] = S[key=16nt+4lg+r][qrow=l15] ----
    f32x4 sacc0 = (f32x4){0.f, 0.f, 0.f, 0.f};
    f32x4 sacc1 = (f32x4){0.f, 0.f, 0.f, 0.f};
#pragma unroll
    for (int kt = 0; kt < 4; ++kt) {
      const int col = lg * 8 + 32 * kt, swz = (l15 & 7) << 3;
      f16x8 kf0 = *(const f16x8*)(Klds + kvh * 4096 + ((l15 * 128 + col) ^ swz));
      f16x8 kf1 = *(const f16x8*)(Klds + kvh * 4096 + (((l15 + 16) * 128 + col) ^ swz));
      sacc0 = __builtin_amdgcn_mfma_f32_16x16x32_f16(kf0, qf[kt], sacc0, 0, 0, 0);
      sacc1 = __builtin_amdgcn_mfma_f32_16x16x32_f16(kf1, qf[kt], sacc1, 0, 0, 0);
    }

    // ---- lane-local softmax (qrow=l15): additive mask, 2-shuffle reductions ----
    f32x4 ma0 = *(const f32x4*)(madd + kvh * 32 + 4 * lg);
    f32x4 ma1 = *(const f32x4*)(madd + kvh * 32 + 16 + 4 * lg);
    f32x4 s0 = sacc0 + ma0, s1 = sacc1 + ma1;
    float tm = fmaxf(fmaxf(fmaxf(s0[0], s0[1]), fmaxf(s0[2], s0[3])),
                     fmaxf(fmaxf(s1[0], s1[1]), fmaxf(s1[2], s1[3])));
    tm = fmaxf(tm, __shfl_xor(tm, 16));
    tm = fmaxf(tm, __shfl_xor(tm, 32));
    const float mn = fmaxf(m_r, tm);
    const float scale = __expf(m_r - mn);
    m_r = mn;
    float p0[4], p1[4];
#pragma unroll
    for (int r = 0; r < 4; ++r) { p0[r] = __expf(s0[r] - mn); p1[r] = __expf(s1[r] - mn); }
    float rs = (p0[0] + p0[1]) + (p0[2] + p0[3]) + (p1[0] + p1[1]) + (p1[2] + p1[3]);
    rs += __shfl_xor(rs, 16);
    rs += __shfl_xor(rs, 32);
    l_r = l_r * scale + rs;
    // P write: Pl[w][qrow=l15][key]
    *(f16x4*)(Pl + w * 640 + l15 * VST + 4 * lg) =
        (f16x4){(f16)p0[0], (f16)p0[1], (f16)p0[2], (f16)p0[3]};
    *(f16x4*)(Pl + w * 640 + l15 * VST + 16 + 4 * lg) =
        (f16x4){(f16)p1[0], (f16)p1[1], (f16)p1[2], (f16)p1[3]};
    // redistribute scale to acco layout (qrow = 4lg+r)
    f32x4 scv;
#pragma unroll
    for (int r = 0; r < 4; ++r) scv[r] = __shfl(scale, 4 * lg + r);
#pragma unroll
    for (int dt = 0; dt < 8; ++dt) acco[dt] *= scv;

    // ---- PV: A=P (row=qrow=l15, k=keys 8lg..8lg+7), B=Vt (n=d=l15+16dt) ----
    f16x8 pa = *(const f16x8*)(Pl + w * 640 + l15 * VST + lg * 8);
#pragma unroll
    for (int dt = 0; dt < 8; ++dt) {
      f16x8 vf = *(const f16x8*)(Vt + kvh * 5120 + (l15 + 16 * dt) * VST + lg * 8);
      acco[dt] = __builtin_amdgcn_mfma_f32_16x16x32_f16(pa, vf, acco[dt], 0, 0, 0);
    }
    __syncthreads();
  }

  // ---- epilogue: merge the two kv-halves (LDS overlay safe past final barrier) ----
  if (kvh == 1) {
#pragma unroll
    for (int r = 0; r < 4; ++r) {
      const int row = 4 * lg + r;
#pragma unroll
      for (int dt = 0; dt < 8; ++dt)
        mrg[rowgrp * 2112 + row * 132 + l15 + 16 * dt] = acco[dt][r];
    }
    if (lg == 0) {
      mlb[rowgrp * 32 + l15 * 2]     = m_r;
      mlb[rowgrp * 32 + l15 * 2 + 1] = l_r;
    }
  }
  __syncthreads();
  if (kvh == 0) {
    float m1[4], l1[4];
#pragma unroll
    for (int r = 0; r < 4; ++r) {
      m1[r] = __shfl(m_r, 4 * lg + r);
      l1[r] = __shfl(l_r, 4 * lg + r);
    }
#pragma unroll
    for (int r = 0; r < 4; ++r) {
      const int row = 4 * lg + r;
      const float m2 = mlb[rowgrp * 32 + row * 2];
      const float l2 = mlb[rowgrp * 32 + row * 2 + 1];
      const float mm = fmaxf(m1[r], m2);
      const float e1 = __expf(m1[r] - mm);
      const float e2 = __expf(m2 - mm);
      const float inv = 1.0f / (l1[r] * e1 + l2 * e2);
      float* op = O + ((size_t)b * S_ + q0 + 16 * rowgrp + row) * D_ + l15;
#pragma unroll
      for (int dt = 0; dt < 8; ++dt)
        op[16 * dt] = (acco[dt][r] * e1 + mrg[rowgrp * 2112 + row * 132 + l15 + 16 * dt] * e2) * inv;
    }
  }
}

extern "C" void kernel_launch(void* const* d_in, const int* in_sizes, int n_in,
                              void* d_out, int out_size, void* d_ws, size_t ws_size,
                              hipStream_t stream) {
  const float* q = (const float*)d_in[0];
  const float* k = (const float*)d_in[1];
  const float* v = (const float*)d_in[2];
  const void*  m = d_in[3];
  float* o = (float*)d_out;
  dim3 grid(S_ / QBLK, B_);
  dim3 block(512);
  attn_fwd<<<grid, block, 0, stream>>>(q, k, v, m, o);
}